// Round 18
// baseline (397.894 us; speedup 1.0000x reference)
//
#include <hip/hip_runtime.h>

// MultiHeadDiffAttention: B=2, T=2048, C=1024, H=16 (v-heads), 2H=32 (q/k heads),
// D=32, Dv=64. prep -> qkv GEMM (256x128 tile, 512 thr, 2-phase dbuf, fused
// RoPE/V epilogue) -> KV-split swapped-QK^T flash attention (m=0 softmax,
// Os overlaid on Ks/Vs LDS -> 16.9 KB/block -> ~8 blocks/CU) ->
// merge+diff+RMS -> out GEMM (counted pipeline).

typedef unsigned short u16;
typedef __bf16 bf16x8 __attribute__((ext_vector_type(8)));
typedef float f32x4 __attribute__((ext_vector_type(4)));
typedef float f32x16 __attribute__((ext_vector_type(16)));
typedef unsigned u32x2 __attribute__((ext_vector_type(2)));

__device__ __forceinline__ u16 f2bf(float f) {
  return __builtin_bit_cast(u16, (__bf16)f);
}
__device__ __forceinline__ float bf2f(u16 u) {
  return (float)__builtin_bit_cast(__bf16, u);
}
__device__ __forceinline__ unsigned pk2(float a, float b) {
  return (unsigned)f2bf(a) | ((unsigned)f2bf(b) << 16);
}

// async global->LDS, 16B per lane. LDS dest must be wave-uniform-base + lane*16.
__device__ __forceinline__ void gload16(const u16* g, u16* l) {
  __builtin_amdgcn_global_load_lds(
      (const __attribute__((address_space(1))) unsigned int*)g,
      (__attribute__((address_space(3))) unsigned int*)l, 16, 0, 0);
}

// ------- fused prep: cvt x->bf16 + W transposes + rope table + lambda
// grid 8321: [0,4096) cvt; [4096,7168) Wa T; [7168,8192) Wp T;
// [8192,8320) rope cos/sin table (2048 x 16 float2); 8320: lambda scalar.
__device__ __forceinline__ void trans_body(const float* __restrict__ in,
                                           u16* __restrict__ out, int R, int Cn,
                                           int bx, int by, float (*tile)[33],
                                           int tx, int ty) {
  const int c0 = bx * 32, r0 = by * 32;
#pragma unroll
  for (int rr = 0; rr < 4; ++rr)
    tile[ty + rr * 8][tx] = in[(size_t)(r0 + ty + rr * 8) * Cn + c0 + tx];
  __syncthreads();
#pragma unroll
  for (int rr = 0; rr < 4; ++rr)
    out[(size_t)(c0 + ty + rr * 8) * R + r0 + tx] = f2bf(tile[tx][ty + rr * 8]);
}

__global__ __launch_bounds__(256) void prep_kernel(
    const float* __restrict__ x, const float* __restrict__ Wa,
    const float* __restrict__ Wp, const float* __restrict__ lq1,
    const float* __restrict__ lk1, const float* __restrict__ lq2,
    const float* __restrict__ lk2, u16* __restrict__ xb, u16* __restrict__ WaT,
    u16* __restrict__ WpT, float2* __restrict__ Tab, float* __restrict__ lamp) {
  __shared__ float tile[32][33];
  const int id = blockIdx.x;
  const int tx = threadIdx.x & 31, ty = threadIdx.x >> 5;
  if (id < 4096) {
    const int i = id * 256 + threadIdx.x;
    float4 v = ((const float4*)x)[i];
    ushort4 o;
    o.x = f2bf(v.x); o.y = f2bf(v.y); o.z = f2bf(v.z); o.w = f2bf(v.w);
    ((ushort4*)xb)[i] = o;
  } else if (id < 7168) {
    const int t = id - 4096;
    trans_body(Wa, WaT, 1024, 3072, t % 96, t / 96, tile, tx, ty);
  } else if (id < 8192) {
    const int t = id - 7168;
    trans_body(Wp, WpT, 1024, 1024, t & 31, t >> 5, tile, tx, ty);
  } else if (id < 8320) {
    const int idx = (id - 8192) * 256 + threadIdx.x;  // 0..32767
    const int t = idx >> 4, i = idx & 15;
    const float theta = exp2f(-0.83048202372184059f * (float)i);  // 10000^(-i/16)
    float sn, cs;
    sincosf((float)t * theta, &sn, &cs);
    Tab[idx] = make_float2(cs, sn);
  } else if (threadIdx.x == 0) {
    float d1 = 0.f, d2 = 0.f;
#pragma unroll
    for (int i = 0; i < 32; ++i) {
      d1 += lq1[i] * lk1[i];
      d2 += lq2[i] * lk2[i];
    }
    *lamp = expf(d1) - expf(d2) + 0.2f;
  }
}

// ------- qkv GEMM: 256x128 tile, 512 thr (8 waves 4x2, wave tile 64x64),
// 2-phase dbuf gload_lds, fused RoPE/V epilogue. grid (24,16) = 384 blocks.
__global__ __launch_bounds__(512, 4) void gemm_qkv_kernel(
    const u16* __restrict__ A, const u16* __restrict__ BT,
    u16* __restrict__ Q, u16* __restrict__ K, u16* __restrict__ VT,
    const float2* __restrict__ Tab) {
  const int Kdim = 1024;
  __shared__ u16 SH[24576];  // [2][As 8192 | Bs 4096] u16
  const int tid = threadIdx.x;
  const int l = tid & 63;
  const int w = tid >> 6;           // 0..7
  const int nwgx = gridDim.x;       // 24
  const int lin = blockIdx.x + nwgx * blockIdx.y;
  const int cpx = (nwgx * gridDim.y) >> 3;  // 48
  const int swz = (lin & 7) * cpx + (lin >> 3);
  const int bm = swz / nwgx, bn = swz % nwgx;   // bm 0..15, bn 0..23
  const int wm = w >> 1, wn = w & 1;            // wave tile 64x64
  const int rowA0 = bm * 256, rowB0 = bn * 128;
  const int r_ = tid >> 2;          // 0..127
  const int s_ = (tid & 3) * 8;
  const u16* Ag0 = &A[(size_t)(rowA0 + r_) * Kdim + s_];
  const u16* Ag1 = Ag0 + (size_t)128 * Kdim;
  const u16* Bg = &BT[(size_t)(rowB0 + r_) * Kdim + s_];
  f32x4 acc[4][4] = {};
  // prologue: stage buf 0 (k0=0)
  gload16(Ag0, &SH[tid * 8]);
  gload16(Ag1, &SH[4096 + tid * 8]);
  gload16(Bg, &SH[8192 + tid * 8]);
  __syncthreads();
  int cur = 0;
  for (int t = 0; t < 32; ++t) {
    const u16* Asc = SH + cur * 12288;
    const u16* Bsc = Asc + 8192;
    if (t + 1 < 32) {  // stage next tile into other buffer (async)
      u16* D = SH + (cur ^ 1) * 12288;
      const int k1 = (t + 1) * 32;
      gload16(Ag0 + k1, &D[tid * 8]);
      gload16(Ag1 + k1, &D[4096 + tid * 8]);
      gload16(Bg + k1, &D[8192 + tid * 8]);
    }
    bf16x8 a[4], b[4];
#pragma unroll
    for (int i = 0; i < 4; ++i)
      a[i] = *(const bf16x8*)&Asc[(wm * 64 + i * 16 + (l & 15)) * 32 + (l >> 4) * 8];
#pragma unroll
    for (int j = 0; j < 4; ++j)
      b[j] = *(const bf16x8*)&Bsc[(wn * 64 + j * 16 + (l & 15)) * 32 + (l >> 4) * 8];
    __builtin_amdgcn_s_setprio(1);
#pragma unroll
    for (int i = 0; i < 4; ++i)
#pragma unroll
      for (int j = 0; j < 4; ++j)
        acc[i][j] = __builtin_amdgcn_mfma_f32_16x16x32_bf16(a[i], b[j], acc[i][j], 0, 0, 0);
    __builtin_amdgcn_s_setprio(0);
    __syncthreads();  // drains this step's gloads AFTER compute; next buf ready
    cur ^= 1;
  }
  const int cr = (l >> 4) * 4;
  const int cc = l & 15;
  const int region = bn >> 3;   // 0=q, 1=k, 2=v (block-uniform)
  const int b_ = rowA0 >> 11, tb = rowA0 & 2047;
  if (region < 2) {
    const float qsc_ = (region == 0) ? 0.25503486f : 1.0f;  // 1/sqrt(32)*log2e | 1
    u16* dst = (region == 0) ? Q : K;
#pragma unroll
    for (int i = 0; i < 4; ++i) {
      const int trow0 = wm * 64 + i * 16 + cr;
#pragma unroll
      for (int j = 0; j < 4; ++j) {
        const int c = (bn & 7) * 128 + wn * 64 + j * 16 + cc;  // 0..1023
        const int hh = c >> 5, d = c & 31;
        const int ii = d >> 1;
        const float sgn = (d & 1) ? 1.0f : -1.0f;
        const size_t base = (size_t)(b_ * 32 + hh) * 2048;
#pragma unroll
        for (int r = 0; r < 4; ++r) {
          const int t = tb + trow0 + r;
          const float2 cs = Tab[t * 16 + ii];
          const float xv = acc[i][j][r];
          const float px = __shfl_xor(xv, 1, 64);
          dst[(base + t) * 32 + d] = f2bf((xv * cs.x + sgn * px * cs.y) * qsc_);
        }
      }
    }
  } else {
#pragma unroll
    for (int i = 0; i < 4; ++i) {
      const int t0 = tb + wm * 64 + i * 16 + cr;
#pragma unroll
      for (int j = 0; j < 4; ++j) {
        const int c3 = (bn & 7) * 128 + wn * 64 + j * 16 + cc;  // 0..1023
        const int hv = c3 >> 6, dv = c3 & 63;
        ushort4 ov;
        ov.x = f2bf(acc[i][j][0]);
        ov.y = f2bf(acc[i][j][1]);
        ov.z = f2bf(acc[i][j][2]);
        ov.w = f2bf(acc[i][j][3]);
        *(ushort4*)&VT[((size_t)(b_ * 16 + hv) * 64 + dv) * 2048 + t0] = ov;
      }
    }
  }
}

// --------------- out GEMM: 64x128 tile, counted-vmcnt pipeline, fp32 out.
__global__ __launch_bounds__(256, 3) void gemm_out_kernel(
    const u16* __restrict__ A, const u16* __restrict__ BT, float* __restrict__ Cout,
    int Mdim, int Ndim, int Kdim) {
  __shared__ u16 SH[24576];  // [4][As 2048 | Bs 4096] u16
  const int tid = threadIdx.x;
  const int l = tid & 63;
  const int w = tid >> 6;
  const int nwgx = gridDim.x;
  const int lin = blockIdx.x + nwgx * blockIdx.y;
  const int cpx = (nwgx * gridDim.y) >> 3;
  const int swz = (lin & 7) * cpx + (lin >> 3);
  const int bm = swz / nwgx, bn = swz % nwgx;
  const int wm = w >> 1, wn = w & 1;   // wave tile 32x64
  const int rowA0 = bm * 64, rowB0 = bn * 128;
  const int r_ = tid >> 2;
  const int s_ = (tid & 3) * 8;
  const u16* Ag = &A[(size_t)(rowA0 + r_) * Kdim + s_];
  const u16* Bg = &BT[(size_t)(rowB0 + r_) * Kdim + s_];
  const size_t rstride = (size_t)64 * Kdim;
  f32x4 acc[2][4] = {};
  const int nt = Kdim >> 5;  // 32
#pragma unroll
  for (int p = 0; p < 3; ++p) {
    u16* D = SH + p * 6144;
    const int k1 = p * 32;
    gload16(Ag + k1, &D[tid * 8]);
    gload16(Bg + k1, &D[2048 + tid * 8]);
    gload16(Bg + rstride + k1, &D[4096 + tid * 8]);
  }
  asm volatile("s_waitcnt vmcnt(6)" ::: "memory");
  __builtin_amdgcn_s_barrier();
  __builtin_amdgcn_sched_barrier(0);
  for (int t = 0; t < nt; ++t) {
    if (t + 3 < nt) {
      u16* D = SH + ((t + 3) & 3) * 6144;
      const int k1 = (t + 3) * 32;
      gload16(Ag + k1, &D[tid * 8]);
      gload16(Bg + k1, &D[2048 + tid * 8]);
      gload16(Bg + rstride + k1, &D[4096 + tid * 8]);
    }
    const u16* Asc = SH + (t & 3) * 6144;
    const u16* Bsc = Asc + 2048;
    bf16x8 a[2], b[4];
#pragma unroll
    for (int i = 0; i < 2; ++i)
      a[i] = *(const bf16x8*)&Asc[(wm * 32 + i * 16 + (l & 15)) * 32 + (l >> 4) * 8];
#pragma unroll
    for (int j = 0; j < 4; ++j)
      b[j] = *(const bf16x8*)&Bsc[(wn * 64 + j * 16 + (l & 15)) * 32 + (l >> 4) * 8];
    __builtin_amdgcn_s_setprio(1);
#pragma unroll
    for (int i = 0; i < 2; ++i)
#pragma unroll
      for (int j = 0; j < 4; ++j)
        acc[i][j] = __builtin_amdgcn_mfma_f32_16x16x32_bf16(a[i], b[j], acc[i][j], 0, 0, 0);
    __builtin_amdgcn_s_setprio(0);
    if (t + 1 < nt) {
      if (t + 3 < nt)
        asm volatile("s_waitcnt vmcnt(6)" ::: "memory");
      else if (t + 2 < nt)
        asm volatile("s_waitcnt vmcnt(3)" ::: "memory");
      else
        asm volatile("s_waitcnt vmcnt(0)" ::: "memory");
      __builtin_amdgcn_s_barrier();
      __builtin_amdgcn_sched_barrier(0);
    }
  }
  const int cr = (l >> 4) * 4;
  const int cc = l & 15;
#pragma unroll
  for (int i = 0; i < 2; ++i)
#pragma unroll
    for (int j = 0; j < 4; ++j)
#pragma unroll
      for (int r = 0; r < 4; ++r) {
        const int row = rowA0 + wm * 32 + i * 16 + cr + r;
        const int col = rowB0 + wn * 64 + j * 16 + cc;
        Cout[(size_t)row * Ndim + col] = acc[i][j][r];
      }
}

// ---------------------------------------------------------------- flash attention
// Swapped QK^T, 32x32x16 MFMA, exp2-domain, m=0 fixed softmax. KV-split:
// block x = (pp, hf); q-tile pp (slot=hf) and 15-pp (slot=hf^1); 17 steps/block.
// Os staging OVERLAYS Ks/Vs (used only after the step loop; barriers separate)
// -> LDS 16.9 KB/block -> ~8 blocks/CU residency (VGPR-capped).
__global__ __launch_bounds__(256, 6) void attn_kernel(const u16* __restrict__ Q,
                                                      const u16* __restrict__ K,
                                                      const u16* __restrict__ VT,
                                                      u16* __restrict__ PO0,
                                                      u16* __restrict__ PO1,
                                                      float* __restrict__ ML) {
  __shared__ u16 LDS[8448];         // Ks[64*34] | Vs[64*66] during loop; Os[4*32*66] after
  u16* Ks = LDS;                    // [k=64][d=32], stride 34 (17-bank step)
  u16* Vs = LDS + 2176;             // [dv=64][k=64], stride 66 (33-bank step)
  const int tid = threadIdx.x, l = tid & 63, w = tid >> 6;
  const int pp = blockIdx.x & 7, hf = blockIdx.x >> 3;
  const int h = blockIdx.y, b = blockIdx.z;
  const size_t qkbase = (size_t)(b * 32 + h) * 2048;
  const size_t vtb = (size_t)(b * 16 + (h & 15)) * 64;
  const int lq = l & 31, hi = l >> 5;
  const f32x16 z16 = {};
  const int krow = tid >> 2, ksl = (tid & 3) * 8;   // K tile: 1 uint4/thread
  const int dva = tid >> 3, vsl = (tid & 7) * 8;    // V tile: 2 uint4/thread
  const int dvb = dva + 32;
  const __bf16 one1 = (__bf16)1.0f;
  const bf16x8 ones = {one1, one1, one1, one1, one1, one1, one1, one1};

  for (int halfidx = 0; halfidx < 2; ++halfidx) {
    const int qt = halfidx ? (15 - pp) : pp;
    const int slot = hf ^ halfidx;
    const int s_begin = slot ? (qt + 1) : 0;
    const int s_end = slot ? (2 * qt + 2) : (qt + 1);
    const int q0 = qt * 128;
    const int qw = q0 + w * 32;
    const int q = qw + lq;
    const bf16x8 qf0 = *(const bf16x8*)&Q[(qkbase + q) * 32 + hi * 8];
    const bf16x8 qf1 = *(const bf16x8*)&Q[(qkbase + q) * 32 + 16 + hi * 8];
    f32x16 olo = {}, ohi = {}, lacc = {};
    // prologue prefetch into regs
    uint4 kreg = *(const uint4*)&K[(qkbase + s_begin * 64 + krow) * 32 + ksl];
    uint4 vreg0 = *(const uint4*)&VT[(vtb + dva) * 2048 + s_begin * 64 + vsl];
    uint4 vreg1 = *(const uint4*)&VT[(vtb + dvb) * 2048 + s_begin * 64 + vsl];
    for (int s = s_begin; s < s_end; ++s) {
      const int kb = s * 64;
      *(uint4*)&Ks[krow * 34 + ksl] = kreg;
      *(uint4*)&Vs[dva * 66 + vsl] = vreg0;
      *(uint4*)&Vs[dvb * 66 + vsl] = vreg1;
      // prefetch next step (issued before barrier; latency hides under compute)
      const int sn = (s + 1 < s_end) ? (s + 1) : s;
      kreg = *(const uint4*)&K[(qkbase + sn * 64 + krow) * 32 + ksl];
      vreg0 = *(const uint4*)&VT[(vtb + dva) * 2048 + sn * 64 + vsl];
      vreg1 = *(const uint4*)&VT[(vtb + dvb) * 2048 + sn * 64 + vsl];
      __syncthreads();
      if (qw + 31 >= kb) {  // wave-uniform skip of fully-masked waves
        // S^T[k][q] = K·Q^T (pre-scaled, exp2 domain)
        f32x16 s0_, s1_;
        {
          const bf16x8 ka0 = *(const bf16x8*)&Ks[lq * 34 + hi * 8];
          const bf16x8 ka1 = *(const bf16x8*)&Ks[lq * 34 + 16 + hi * 8];
          const bf16x8 kc0 = *(const bf16x8*)&Ks[(32 + lq) * 34 + hi * 8];
          const bf16x8 kc1 = *(const bf16x8*)&Ks[(32 + lq) * 34 + 16 + hi * 8];
          __builtin_amdgcn_s_setprio(1);
          s0_ = __builtin_amdgcn_mfma_f32_32x32x16_bf16(ka0, qf0, z16, 0, 0, 0);
          s0_ = __builtin_amdgcn_mfma_f32_32x32x16_bf16(ka1, qf1, s0_, 0, 0, 0);
          s1_ = __builtin_amdgcn_mfma_f32_32x32x16_bf16(kc0, qf0, z16, 0, 0, 0);
          s1_ = __builtin_amdgcn_mfma_f32_32x32x16_bf16(kc1, qf1, s1_, 0, 0, 0);
          __builtin_amdgcn_s_setprio(0);
        }
        const bool nm = (kb + 63 > qw);
        if (nm) {
#pragma unroll
          for (int r = 0; r < 16; ++r) {
            const int kr = (r & 3) + 8 * (r >> 2) + 4 * hi;
            if (kb + kr > q) s0_[r] = -1e30f;
            if (kb + 32 + kr > q) s1_[r] = -1e30f;
          }
        }
        // P = exp2(S) directly (no max subtraction); masked -> exp2(-1e30)=0
#pragma unroll
        for (int r = 0; r < 16; ++r) {
          s0_[r] = __builtin_amdgcn_exp2f(s0_[r]);
          s1_[r] = __builtin_amdgcn_exp2f(s1_[r]);
        }
        // pack P -> bf16 words
        unsigned pw[16];
#pragma unroll
        for (int j = 0; j < 8; ++j) {
          pw[j] = pk2(s0_[2 * j], s0_[2 * j + 1]);
          pw[8 + j] = pk2(s1_[2 * j], s1_[2 * j + 1]);
        }
        // half-exchange -> P^T B-fragments
        bf16x8 pa[4];
#pragma unroll
        for (int fidx = 0; fidx < 4; ++fidx) {
          const unsigned* wt = &pw[fidx * 4];
          union { unsigned u[4]; bf16x8 v; } fr;
#if __has_builtin(__builtin_amdgcn_permlane32_swap)
          const u32x2 rA = __builtin_amdgcn_permlane32_swap(wt[0], wt[2], false, false);
          const u32x2 rB = __builtin_amdgcn_permlane32_swap(wt[1], wt[3], false, false);
          fr.u[0] = rA[0]; fr.u[1] = rB[0]; fr.u[2] = rA[1]; fr.u[3] = rB[1];
#else
          const unsigned ua = hi ? wt[0] : wt[2];
          const unsigned ub = hi ? wt[1] : wt[3];
          const unsigned sa = __shfl_xor(ua, 32, 64);
          const unsigned sb = __shfl_xor(ub, 32, 64);
          fr.u[0] = hi ? sa : wt[0];
          fr.u[1] = hi ? sb : wt[1];
          fr.u[2] = hi ? wt[2] : sa;
          fr.u[3] = hi ? wt[3] : sb;
#endif
          pa[fidx] = fr.v;
        }
        // O^T += V^T·P^T; row-sums via ones-fragment on the MFMA pipe
        __builtin_amdgcn_s_setprio(1);
#pragma unroll
        for (int ks = 0; ks < 4; ++ks) {
          const bf16x8 va = *(const bf16x8*)&Vs[lq * 66 + ks * 16 + hi * 8];
          const bf16x8 vb = *(const bf16x8*)&Vs[(32 + lq) * 66 + ks * 16 + hi * 8];
          olo = __builtin_amdgcn_mfma_f32_32x32x16_bf16(va, pa[ks], olo, 0, 0, 0);
          ohi = __builtin_amdgcn_mfma_f32_32x32x16_bf16(vb, pa[ks], ohi, 0, 0, 0);
          lacc = __builtin_amdgcn_mfma_f32_32x32x16_bf16(ones, pa[ks], lacc, 0, 0, 0);
        }
        __builtin_amdgcn_s_setprio(0);
      }
      __syncthreads();  // also separates last compute from Os overlay writes
    }
    // epilogue: write l + self-normalized partial O (bf16, coalesced).
    // Os overlays Ks/Vs — safe: loop's final barrier is above, and the barrier
    // after the PO copy protects it from the next half's K/V writes.
    const float lsum = lacc[0];
    const float inv = (lsum > 0.f) ? (1.0f / lsum) : 0.f;
    if (hi == 0)
      ML[(size_t)slot * 131072 + qkbase + q] = lsum;
    u16* Ow = &LDS[(w * 32 + lq) * 66];
#pragma unroll
    for (int g = 0; g < 4; ++g) {
      const int d0 = 8 * g + 4 * hi;
      *(unsigned*)&Ow[d0] = pk2(olo[4 * g] * inv, olo[4 * g + 1] * inv);
      *(unsigned*)&Ow[d0 + 2] = pk2(olo[4 * g + 2] * inv, olo[4 * g + 3] * inv);
      *(unsigned*)&Ow[32 + d0] = pk2(ohi[4 * g] * inv, ohi[4 * g + 1] * inv);
      *(unsigned*)&Ow[32 + d0 + 2] = pk2(ohi[4 * g + 2] * inv, ohi[4 * g + 3] * inv);
    }
    __syncthreads();
    u16* PO = slot ? PO1 : PO0;
    for (int s2 = tid; s2 < 1024; s2 += 256) {
      const int wv = s2 >> 8, qq = (s2 >> 3) & 31, sl = (s2 & 7) * 8;
      *(uint4*)&PO[(qkbase + q0 + wv * 32 + qq) * 64 + sl] =
          *(const uint4*)&LDS[(wv * 32 + qq) * 66 + sl];
    }
    __syncthreads();  // protect Os reads from next half's K/V writes
  }
}

// ---------------------------------------- fused partial-merge + diff + RMS
__global__ __launch_bounds__(256) void diff_rms_kernel(
    const u16* __restrict__ PO0, const u16* __restrict__ PO1,
    const float* __restrict__ ML, const float* __restrict__ lamp,
    u16* __restrict__ Mb) {
  const int g = threadIdx.x >> 5;          // 0..7 (row within block)
  const int dl = (threadIdx.x & 31) * 2;   // d offset
  const int ridx = blockIdx.x * 8 + g;     // (b,h,t): 0..65535
  const int b = ridx >> 15, rem = ridx & 32767, h = rem >> 11, t = rem & 2047;
  const float lam = *lamp;
  const size_t row1 = (size_t)(b * 32 + h) * 2048 + t;
  const size_t row2 = (size_t)(b * 32 + 16 + h) * 2048 + t;
  const float lA1 = ML[row1], lB1 = ML[131072 + row1];
  const float lA2 = ML[row2], lB2 = ML[131072 + row2];
  const float i1 = 1.0f / (lA1 + lB1);
  const float wa1 = lA1 * i1, wb1 = lB1 * i1;
  const float i2 = 1.0f / (lA2 + lB2);
  const float wa2 = lA2 * i2, wb2 = lB2 * i2;
  const ushort2 p01 = *(const ushort2*)&PO0[row1 * 64 + dl];
  const ushort2 p11 = *(const ushort2*)&PO1[row1 * 64 + dl];
  const ushort2 p02 = *(const ushort2*)&PO0[row2 * 64 + dl];
  const ushort2 p12 = *(const ushort2*)&PO1[row2 * 64 + dl];
  const float a1x = wa1 * bf2f(p01.x) + wb1 * bf2f(p11.x);
  const float a1y = wa1 * bf2f(p01.y) + wb1 * bf2f(p11.y);
  const float a2x = wa2 * bf2f(p02.x) + wb2 * bf2f(p12.x);
  const float a2y = wa2 * bf2f(p02.y) + wb2 * bf2f(p12.y);
  const float df0 = a1x - lam * a2x;
  const float df1 = a1y - lam * a2y;
  float ss = df0 * df0 + df1 * df1;
  ss += __shfl_xor(ss, 1, 64);
  ss += __shfl_xor(ss, 2, 64);
  ss += __shfl_xor(ss, 4, 64);
  ss += __shfl_xor(ss, 8, 64);
  ss += __shfl_xor(ss, 16, 64);
  const float rms = rsqrtf(ss * (1.0f / 64.0f) + 1e-5f);
  ushort2 o;
  o.x = f2bf(0.8f * df0 * rms);
  o.y = f2bf(0.8f * df1 * rms);
  *(ushort2*)&Mb[((size_t)(b * 2048 + t)) * 1024 + h * 64 + dl] = o;
}

// ---------------------------------------------------------------- launch
extern "C" void kernel_launch(void* const* d_in, const int* in_sizes, int n_in,
                              void* d_out, int out_size, void* d_ws, size_t ws_size,
                              hipStream_t stream) {
  const float* x = (const float*)d_in[0];
  const float* Wa = (const float*)d_in[1];
  const float* Wp = (const float*)d_in[2];
  const float* lq1 = (const float*)d_in[3];
  const float* lk1 = (const float*)d_in[4];
  const float* lq2 = (const float*)d_in[5];
  const float* lk2 = (const float*)d_in[6];
  if (ws_size < (size_t)(64u << 20)) return;  // need 64 MiB scratch

  char* ws = (char*)d_ws;
  u16* Qarr = (u16*)(ws);                        // 8 MiB
  u16* Karr = (u16*)(ws + (8u << 20));           // 8 MiB
  u16* VTarr = (u16*)(ws + (16u << 20));         // 8 MiB
  u16* WpT = (u16*)(ws + (24u << 20));           // 2 MiB
  char* arena = ws + (26u << 20);                // 38 MiB arena
  u16* xb = (u16*)(arena);                       // 8 MiB  (dead after gemm_qkv)
  u16* WaT = (u16*)(arena + (8u << 20));         // 6 MiB  (dead after gemm_qkv)
  float2* Tab = (float2*)(arena + (14u << 20));  // 256 KiB (dead after gemm_qkv)
  u16* PO0 = (u16*)(arena);                      // 16 MiB partial O (slot 0)
  u16* PO1 = (u16*)(arena + (16u << 20));        // 16 MiB partial O (slot 1)
  float* ML = (float*)(arena + (32u << 20));     // 1 MiB l per row per slot
  float* lamp = (float*)(arena + (33u << 20));   // 4 B lambda (survives attn)
  u16* Mbuf = Qarr;                              // 8 MiB (overlays Q after attn)

  prep_kernel<<<8321, 256, 0, stream>>>(x, Wa, Wp, lq1, lk1, lq2, lk2,
                                        xb, WaT, WpT, Tab, lamp);
  gemm_qkv_kernel<<<dim3(24, 16), 512, 0, stream>>>(xb, WaT, Qarr, Karr, VTarr, Tab);
  attn_kernel<<<dim3(16, 32, 2), 256, 0, stream>>>(Qarr, Karr, VTarr, PO0, PO1, ML);
  diff_rms_kernel<<<8192, 256, 0, stream>>>(PO0, PO1, ML, lamp, Mbuf);
  gemm_out_kernel<<<dim3(8, 64), 256, 0, stream>>>(Mbuf, WpT, (float*)d_out, 4096, 1024, 1024);
}

// Round 19
// 186.167 us; speedup vs baseline: 2.1373x; 2.1373x over previous
//
#include <hip/hip_runtime.h>

// MultiHeadDiffAttention: B=2, T=2048, C=1024, H=16 (v-heads), 2H=32 (q/k heads),
// D=32, Dv=64. prep -> qkv GEMM (256x128 tile, 512 thr, 2-phase dbuf, fused
// RoPE/V epilogue) -> KV-split swapped-QK^T flash attention (m=0 softmax,
// Os overlaid on Ks/Vs LDS = 16.9 KB/block -> 8 blocks/CU at VGPR 64;
// launch_bounds (256,4) so the allocator is NOT starved) ->
// merge+diff+RMS -> out GEMM (counted pipeline).

typedef unsigned short u16;
typedef __bf16 bf16x8 __attribute__((ext_vector_type(8)));
typedef float f32x4 __attribute__((ext_vector_type(4)));
typedef float f32x16 __attribute__((ext_vector_type(16)));
typedef unsigned u32x2 __attribute__((ext_vector_type(2)));

__device__ __forceinline__ u16 f2bf(float f) {
  return __builtin_bit_cast(u16, (__bf16)f);
}
__device__ __forceinline__ float bf2f(u16 u) {
  return (float)__builtin_bit_cast(__bf16, u);
}
__device__ __forceinline__ unsigned pk2(float a, float b) {
  return (unsigned)f2bf(a) | ((unsigned)f2bf(b) << 16);
}

// async global->LDS, 16B per lane. LDS dest must be wave-uniform-base + lane*16.
__device__ __forceinline__ void gload16(const u16* g, u16* l) {
  __builtin_amdgcn_global_load_lds(
      (const __attribute__((address_space(1))) unsigned int*)g,
      (__attribute__((address_space(3))) unsigned int*)l, 16, 0, 0);
}

// ------- fused prep: cvt x->bf16 + W transposes + rope table + lambda
// grid 8321: [0,4096) cvt; [4096,7168) Wa T; [7168,8192) Wp T;
// [8192,8320) rope cos/sin table (2048 x 16 float2); 8320: lambda scalar.
__device__ __forceinline__ void trans_body(const float* __restrict__ in,
                                           u16* __restrict__ out, int R, int Cn,
                                           int bx, int by, float (*tile)[33],
                                           int tx, int ty) {
  const int c0 = bx * 32, r0 = by * 32;
#pragma unroll
  for (int rr = 0; rr < 4; ++rr)
    tile[ty + rr * 8][tx] = in[(size_t)(r0 + ty + rr * 8) * Cn + c0 + tx];
  __syncthreads();
#pragma unroll
  for (int rr = 0; rr < 4; ++rr)
    out[(size_t)(c0 + ty + rr * 8) * R + r0 + tx] = f2bf(tile[tx][ty + rr * 8]);
}

__global__ __launch_bounds__(256) void prep_kernel(
    const float* __restrict__ x, const float* __restrict__ Wa,
    const float* __restrict__ Wp, const float* __restrict__ lq1,
    const float* __restrict__ lk1, const float* __restrict__ lq2,
    const float* __restrict__ lk2, u16* __restrict__ xb, u16* __restrict__ WaT,
    u16* __restrict__ WpT, float2* __restrict__ Tab, float* __restrict__ lamp) {
  __shared__ float tile[32][33];
  const int id = blockIdx.x;
  const int tx = threadIdx.x & 31, ty = threadIdx.x >> 5;
  if (id < 4096) {
    const int i = id * 256 + threadIdx.x;
    float4 v = ((const float4*)x)[i];
    ushort4 o;
    o.x = f2bf(v.x); o.y = f2bf(v.y); o.z = f2bf(v.z); o.w = f2bf(v.w);
    ((ushort4*)xb)[i] = o;
  } else if (id < 7168) {
    const int t = id - 4096;
    trans_body(Wa, WaT, 1024, 3072, t % 96, t / 96, tile, tx, ty);
  } else if (id < 8192) {
    const int t = id - 7168;
    trans_body(Wp, WpT, 1024, 1024, t & 31, t >> 5, tile, tx, ty);
  } else if (id < 8320) {
    const int idx = (id - 8192) * 256 + threadIdx.x;  // 0..32767
    const int t = idx >> 4, i = idx & 15;
    const float theta = exp2f(-0.83048202372184059f * (float)i);  // 10000^(-i/16)
    float sn, cs;
    sincosf((float)t * theta, &sn, &cs);
    Tab[idx] = make_float2(cs, sn);
  } else if (threadIdx.x == 0) {
    float d1 = 0.f, d2 = 0.f;
#pragma unroll
    for (int i = 0; i < 32; ++i) {
      d1 += lq1[i] * lk1[i];
      d2 += lq2[i] * lk2[i];
    }
    *lamp = expf(d1) - expf(d2) + 0.2f;
  }
}

// ------- qkv GEMM: 256x128 tile, 512 thr (8 waves 4x2, wave tile 64x64),
// 2-phase dbuf gload_lds, fused RoPE/V epilogue. grid (24,16) = 384 blocks.
__global__ __launch_bounds__(512, 4) void gemm_qkv_kernel(
    const u16* __restrict__ A, const u16* __restrict__ BT,
    u16* __restrict__ Q, u16* __restrict__ K, u16* __restrict__ VT,
    const float2* __restrict__ Tab) {
  const int Kdim = 1024;
  __shared__ u16 SH[24576];  // [2][As 8192 | Bs 4096] u16
  const int tid = threadIdx.x;
  const int l = tid & 63;
  const int w = tid >> 6;           // 0..7
  const int nwgx = gridDim.x;       // 24
  const int lin = blockIdx.x + nwgx * blockIdx.y;
  const int cpx = (nwgx * gridDim.y) >> 3;  // 48
  const int swz = (lin & 7) * cpx + (lin >> 3);
  const int bm = swz / nwgx, bn = swz % nwgx;   // bm 0..15, bn 0..23
  const int wm = w >> 1, wn = w & 1;            // wave tile 64x64
  const int rowA0 = bm * 256, rowB0 = bn * 128;
  const int r_ = tid >> 2;          // 0..127
  const int s_ = (tid & 3) * 8;
  const u16* Ag0 = &A[(size_t)(rowA0 + r_) * Kdim + s_];
  const u16* Ag1 = Ag0 + (size_t)128 * Kdim;
  const u16* Bg = &BT[(size_t)(rowB0 + r_) * Kdim + s_];
  f32x4 acc[4][4] = {};
  // prologue: stage buf 0 (k0=0)
  gload16(Ag0, &SH[tid * 8]);
  gload16(Ag1, &SH[4096 + tid * 8]);
  gload16(Bg, &SH[8192 + tid * 8]);
  __syncthreads();
  int cur = 0;
  for (int t = 0; t < 32; ++t) {
    const u16* Asc = SH + cur * 12288;
    const u16* Bsc = Asc + 8192;
    if (t + 1 < 32) {  // stage next tile into other buffer (async)
      u16* D = SH + (cur ^ 1) * 12288;
      const int k1 = (t + 1) * 32;
      gload16(Ag0 + k1, &D[tid * 8]);
      gload16(Ag1 + k1, &D[4096 + tid * 8]);
      gload16(Bg + k1, &D[8192 + tid * 8]);
    }
    bf16x8 a[4], b[4];
#pragma unroll
    for (int i = 0; i < 4; ++i)
      a[i] = *(const bf16x8*)&Asc[(wm * 64 + i * 16 + (l & 15)) * 32 + (l >> 4) * 8];
#pragma unroll
    for (int j = 0; j < 4; ++j)
      b[j] = *(const bf16x8*)&Bsc[(wn * 64 + j * 16 + (l & 15)) * 32 + (l >> 4) * 8];
    __builtin_amdgcn_s_setprio(1);
#pragma unroll
    for (int i = 0; i < 4; ++i)
#pragma unroll
      for (int j = 0; j < 4; ++j)
        acc[i][j] = __builtin_amdgcn_mfma_f32_16x16x32_bf16(a[i], b[j], acc[i][j], 0, 0, 0);
    __builtin_amdgcn_s_setprio(0);
    __syncthreads();  // drains this step's gloads AFTER compute; next buf ready
    cur ^= 1;
  }
  const int cr = (l >> 4) * 4;
  const int cc = l & 15;
  const int region = bn >> 3;   // 0=q, 1=k, 2=v (block-uniform)
  const int b_ = rowA0 >> 11, tb = rowA0 & 2047;
  if (region < 2) {
    const float qsc_ = (region == 0) ? 0.25503486f : 1.0f;  // 1/sqrt(32)*log2e | 1
    u16* dst = (region == 0) ? Q : K;
#pragma unroll
    for (int i = 0; i < 4; ++i) {
      const int trow0 = wm * 64 + i * 16 + cr;
#pragma unroll
      for (int j = 0; j < 4; ++j) {
        const int c = (bn & 7) * 128 + wn * 64 + j * 16 + cc;  // 0..1023
        const int hh = c >> 5, d = c & 31;
        const int ii = d >> 1;
        const float sgn = (d & 1) ? 1.0f : -1.0f;
        const size_t base = (size_t)(b_ * 32 + hh) * 2048;
#pragma unroll
        for (int r = 0; r < 4; ++r) {
          const int t = tb + trow0 + r;
          const float2 cs = Tab[t * 16 + ii];
          const float xv = acc[i][j][r];
          const float px = __shfl_xor(xv, 1, 64);
          dst[(base + t) * 32 + d] = f2bf((xv * cs.x + sgn * px * cs.y) * qsc_);
        }
      }
    }
  } else {
#pragma unroll
    for (int i = 0; i < 4; ++i) {
      const int t0 = tb + wm * 64 + i * 16 + cr;
#pragma unroll
      for (int j = 0; j < 4; ++j) {
        const int c3 = (bn & 7) * 128 + wn * 64 + j * 16 + cc;  // 0..1023
        const int hv = c3 >> 6, dv = c3 & 63;
        ushort4 ov;
        ov.x = f2bf(acc[i][j][0]);
        ov.y = f2bf(acc[i][j][1]);
        ov.z = f2bf(acc[i][j][2]);
        ov.w = f2bf(acc[i][j][3]);
        *(ushort4*)&VT[((size_t)(b_ * 16 + hv) * 64 + dv) * 2048 + t0] = ov;
      }
    }
  }
}

// --------------- out GEMM: 64x128 tile, counted-vmcnt pipeline, fp32 out.
__global__ __launch_bounds__(256, 3) void gemm_out_kernel(
    const u16* __restrict__ A, const u16* __restrict__ BT, float* __restrict__ Cout,
    int Mdim, int Ndim, int Kdim) {
  __shared__ u16 SH[24576];  // [4][As 2048 | Bs 4096] u16
  const int tid = threadIdx.x;
  const int l = tid & 63;
  const int w = tid >> 6;
  const int nwgx = gridDim.x;
  const int lin = blockIdx.x + nwgx * blockIdx.y;
  const int cpx = (nwgx * gridDim.y) >> 3;
  const int swz = (lin & 7) * cpx + (lin >> 3);
  const int bm = swz / nwgx, bn = swz % nwgx;
  const int wm = w >> 1, wn = w & 1;   // wave tile 32x64
  const int rowA0 = bm * 64, rowB0 = bn * 128;
  const int r_ = tid >> 2;
  const int s_ = (tid & 3) * 8;
  const u16* Ag = &A[(size_t)(rowA0 + r_) * Kdim + s_];
  const u16* Bg = &BT[(size_t)(rowB0 + r_) * Kdim + s_];
  const size_t rstride = (size_t)64 * Kdim;
  f32x4 acc[2][4] = {};
  const int nt = Kdim >> 5;  // 32
#pragma unroll
  for (int p = 0; p < 3; ++p) {
    u16* D = SH + p * 6144;
    const int k1 = p * 32;
    gload16(Ag + k1, &D[tid * 8]);
    gload16(Bg + k1, &D[2048 + tid * 8]);
    gload16(Bg + rstride + k1, &D[4096 + tid * 8]);
  }
  asm volatile("s_waitcnt vmcnt(6)" ::: "memory");
  __builtin_amdgcn_s_barrier();
  __builtin_amdgcn_sched_barrier(0);
  for (int t = 0; t < nt; ++t) {
    if (t + 3 < nt) {
      u16* D = SH + ((t + 3) & 3) * 6144;
      const int k1 = (t + 3) * 32;
      gload16(Ag + k1, &D[tid * 8]);
      gload16(Bg + k1, &D[2048 + tid * 8]);
      gload16(Bg + rstride + k1, &D[4096 + tid * 8]);
    }
    const u16* Asc = SH + (t & 3) * 6144;
    const u16* Bsc = Asc + 2048;
    bf16x8 a[2], b[4];
#pragma unroll
    for (int i = 0; i < 2; ++i)
      a[i] = *(const bf16x8*)&Asc[(wm * 32 + i * 16 + (l & 15)) * 32 + (l >> 4) * 8];
#pragma unroll
    for (int j = 0; j < 4; ++j)
      b[j] = *(const bf16x8*)&Bsc[(wn * 64 + j * 16 + (l & 15)) * 32 + (l >> 4) * 8];
    __builtin_amdgcn_s_setprio(1);
#pragma unroll
    for (int i = 0; i < 2; ++i)
#pragma unroll
      for (int j = 0; j < 4; ++j)
        acc[i][j] = __builtin_amdgcn_mfma_f32_16x16x32_bf16(a[i], b[j], acc[i][j], 0, 0, 0);
    __builtin_amdgcn_s_setprio(0);
    if (t + 1 < nt) {
      if (t + 3 < nt)
        asm volatile("s_waitcnt vmcnt(6)" ::: "memory");
      else if (t + 2 < nt)
        asm volatile("s_waitcnt vmcnt(3)" ::: "memory");
      else
        asm volatile("s_waitcnt vmcnt(0)" ::: "memory");
      __builtin_amdgcn_s_barrier();
      __builtin_amdgcn_sched_barrier(0);
    }
  }
  const int cr = (l >> 4) * 4;
  const int cc = l & 15;
#pragma unroll
  for (int i = 0; i < 2; ++i)
#pragma unroll
    for (int j = 0; j < 4; ++j)
#pragma unroll
      for (int r = 0; r < 4; ++r) {
        const int row = rowA0 + wm * 32 + i * 16 + cr + r;
        const int col = rowB0 + wn * 64 + j * 16 + cc;
        Cout[(size_t)row * Ndim + col] = acc[i][j][r];
      }
}

// ---------------------------------------------------------------- flash attention
// Swapped QK^T, 32x32x16 MFMA, exp2-domain, m=0 fixed softmax. KV-split:
// block x = (pp, hf); q-tile pp (slot=hf) and 15-pp (slot=hf^1); 17 steps/block.
// Os staging OVERLAYS Ks/Vs -> LDS 16.9 KB/block; launch_bounds (256,4) keeps
// VGPR at 64 (no spill); residency = min(LDS 9, VGPR 8) = 8 blocks/CU.
__global__ __launch_bounds__(256, 4) void attn_kernel(const u16* __restrict__ Q,
                                                      const u16* __restrict__ K,
                                                      const u16* __restrict__ VT,
                                                      u16* __restrict__ PO0,
                                                      u16* __restrict__ PO1,
                                                      float* __restrict__ ML) {
  __shared__ u16 LDS[8448];         // Ks[64*34] | Vs[64*66] during loop; Os[4*32*66] after
  u16* Ks = LDS;                    // [k=64][d=32], stride 34 (17-bank step)
  u16* Vs = LDS + 2176;             // [dv=64][k=64], stride 66 (33-bank step)
  const int tid = threadIdx.x, l = tid & 63, w = tid >> 6;
  const int pp = blockIdx.x & 7, hf = blockIdx.x >> 3;
  const int h = blockIdx.y, b = blockIdx.z;
  const size_t qkbase = (size_t)(b * 32 + h) * 2048;
  const size_t vtb = (size_t)(b * 16 + (h & 15)) * 64;
  const int lq = l & 31, hi = l >> 5;
  const f32x16 z16 = {};
  const int krow = tid >> 2, ksl = (tid & 3) * 8;   // K tile: 1 uint4/thread
  const int dva = tid >> 3, vsl = (tid & 7) * 8;    // V tile: 2 uint4/thread
  const int dvb = dva + 32;
  const __bf16 one1 = (__bf16)1.0f;
  const bf16x8 ones = {one1, one1, one1, one1, one1, one1, one1, one1};

  for (int halfidx = 0; halfidx < 2; ++halfidx) {
    const int qt = halfidx ? (15 - pp) : pp;
    const int slot = hf ^ halfidx;
    const int s_begin = slot ? (qt + 1) : 0;
    const int s_end = slot ? (2 * qt + 2) : (qt + 1);
    const int q0 = qt * 128;
    const int qw = q0 + w * 32;
    const int q = qw + lq;
    const bf16x8 qf0 = *(const bf16x8*)&Q[(qkbase + q) * 32 + hi * 8];
    const bf16x8 qf1 = *(const bf16x8*)&Q[(qkbase + q) * 32 + 16 + hi * 8];
    f32x16 olo = {}, ohi = {}, lacc = {};
    // prologue prefetch into regs
    uint4 kreg = *(const uint4*)&K[(qkbase + s_begin * 64 + krow) * 32 + ksl];
    uint4 vreg0 = *(const uint4*)&VT[(vtb + dva) * 2048 + s_begin * 64 + vsl];
    uint4 vreg1 = *(const uint4*)&VT[(vtb + dvb) * 2048 + s_begin * 64 + vsl];
    for (int s = s_begin; s < s_end; ++s) {
      const int kb = s * 64;
      *(uint4*)&Ks[krow * 34 + ksl] = kreg;
      *(uint4*)&Vs[dva * 66 + vsl] = vreg0;
      *(uint4*)&Vs[dvb * 66 + vsl] = vreg1;
      // prefetch next step (issued before barrier; latency hides under compute)
      const int sn = (s + 1 < s_end) ? (s + 1) : s;
      kreg = *(const uint4*)&K[(qkbase + sn * 64 + krow) * 32 + ksl];
      vreg0 = *(const uint4*)&VT[(vtb + dva) * 2048 + sn * 64 + vsl];
      vreg1 = *(const uint4*)&VT[(vtb + dvb) * 2048 + sn * 64 + vsl];
      __syncthreads();
      if (qw + 31 >= kb) {  // wave-uniform skip of fully-masked waves
        // S^T[k][q] = K·Q^T (pre-scaled, exp2 domain)
        f32x16 s0_, s1_;
        {
          const bf16x8 ka0 = *(const bf16x8*)&Ks[lq * 34 + hi * 8];
          const bf16x8 ka1 = *(const bf16x8*)&Ks[lq * 34 + 16 + hi * 8];
          const bf16x8 kc0 = *(const bf16x8*)&Ks[(32 + lq) * 34 + hi * 8];
          const bf16x8 kc1 = *(const bf16x8*)&Ks[(32 + lq) * 34 + 16 + hi * 8];
          __builtin_amdgcn_s_setprio(1);
          s0_ = __builtin_amdgcn_mfma_f32_32x32x16_bf16(ka0, qf0, z16, 0, 0, 0);
          s0_ = __builtin_amdgcn_mfma_f32_32x32x16_bf16(ka1, qf1, s0_, 0, 0, 0);
          s1_ = __builtin_amdgcn_mfma_f32_32x32x16_bf16(kc0, qf0, z16, 0, 0, 0);
          s1_ = __builtin_amdgcn_mfma_f32_32x32x16_bf16(kc1, qf1, s1_, 0, 0, 0);
          __builtin_amdgcn_s_setprio(0);
        }
        const bool nm = (kb + 63 > qw);
        if (nm) {
#pragma unroll
          for (int r = 0; r < 16; ++r) {
            const int kr = (r & 3) + 8 * (r >> 2) + 4 * hi;
            if (kb + kr > q) s0_[r] = -1e30f;
            if (kb + 32 + kr > q) s1_[r] = -1e30f;
          }
        }
        // P = exp2(S) directly (no max subtraction); masked -> exp2(-1e30)=0
#pragma unroll
        for (int r = 0; r < 16; ++r) {
          s0_[r] = __builtin_amdgcn_exp2f(s0_[r]);
          s1_[r] = __builtin_amdgcn_exp2f(s1_[r]);
        }
        // pack P -> bf16 words
        unsigned pw[16];
#pragma unroll
        for (int j = 0; j < 8; ++j) {
          pw[j] = pk2(s0_[2 * j], s0_[2 * j + 1]);
          pw[8 + j] = pk2(s1_[2 * j], s1_[2 * j + 1]);
        }
        // half-exchange -> P^T B-fragments
        bf16x8 pa[4];
#pragma unroll
        for (int fidx = 0; fidx < 4; ++fidx) {
          const unsigned* wt = &pw[fidx * 4];
          union { unsigned u[4]; bf16x8 v; } fr;
#if __has_builtin(__builtin_amdgcn_permlane32_swap)
          const u32x2 rA = __builtin_amdgcn_permlane32_swap(wt[0], wt[2], false, false);
          const u32x2 rB = __builtin_amdgcn_permlane32_swap(wt[1], wt[3], false, false);
          fr.u[0] = rA[0]; fr.u[1] = rB[0]; fr.u[2] = rA[1]; fr.u[3] = rB[1];
#else
          const unsigned ua = hi ? wt[0] : wt[2];
          const unsigned ub = hi ? wt[1] : wt[3];
          const unsigned sa = __shfl_xor(ua, 32, 64);
          const unsigned sb = __shfl_xor(ub, 32, 64);
          fr.u[0] = hi ? sa : wt[0];
          fr.u[1] = hi ? sb : wt[1];
          fr.u[2] = hi ? wt[2] : sa;
          fr.u[3] = hi ? wt[3] : sb;
#endif
          pa[fidx] = fr.v;
        }
        // O^T += V^T·P^T; row-sums via ones-fragment on the MFMA pipe
        __builtin_amdgcn_s_setprio(1);
#pragma unroll
        for (int ks = 0; ks < 4; ++ks) {
          const bf16x8 va = *(const bf16x8*)&Vs[lq * 66 + ks * 16 + hi * 8];
          const bf16x8 vb = *(const bf16x8*)&Vs[(32 + lq) * 66 + ks * 16 + hi * 8];
          olo = __builtin_amdgcn_mfma_f32_32x32x16_bf16(va, pa[ks], olo, 0, 0, 0);
          ohi = __builtin_amdgcn_mfma_f32_32x32x16_bf16(vb, pa[ks], ohi, 0, 0, 0);
          lacc = __builtin_amdgcn_mfma_f32_32x32x16_bf16(ones, pa[ks], lacc, 0, 0, 0);
        }
        __builtin_amdgcn_s_setprio(0);
      }
      __syncthreads();  // also separates last compute from Os overlay writes
    }
    // epilogue: write l + self-normalized partial O (bf16, coalesced).
    // Os overlays Ks/Vs — safe: loop's final barrier is above, and the barrier
    // after the PO copy protects it from the next half's K/V writes.
    const float lsum = lacc[0];
    const float inv = (lsum > 0.f) ? (1.0f / lsum) : 0.f;
    if (hi == 0)
      ML[(size_t)slot * 131072 + qkbase + q] = lsum;
    u16* Ow = &LDS[(w * 32 + lq) * 66];
#pragma unroll
    for (int g = 0; g < 4; ++g) {
      const int d0 = 8 * g + 4 * hi;
      *(unsigned*)&Ow[d0] = pk2(olo[4 * g] * inv, olo[4 * g + 1] * inv);
      *(unsigned*)&Ow[d0 + 2] = pk2(olo[4 * g + 2] * inv, olo[4 * g + 3] * inv);
      *(unsigned*)&Ow[32 + d0] = pk2(ohi[4 * g] * inv, ohi[4 * g + 1] * inv);
      *(unsigned*)&Ow[32 + d0 + 2] = pk2(ohi[4 * g + 2] * inv, ohi[4 * g + 3] * inv);
    }
    __syncthreads();
    u16* PO = slot ? PO1 : PO0;
    for (int s2 = tid; s2 < 1024; s2 += 256) {
      const int wv = s2 >> 8, qq = (s2 >> 3) & 31, sl = (s2 & 7) * 8;
      *(uint4*)&PO[(qkbase + q0 + wv * 32 + qq) * 64 + sl] =
          *(const uint4*)&LDS[(wv * 32 + qq) * 66 + sl];
    }
    __syncthreads();  // protect Os reads from next half's K/V writes
  }
}

// ---------------------------------------- fused partial-merge + diff + RMS
__global__ __launch_bounds__(256) void diff_rms_kernel(
    const u16* __restrict__ PO0, const u16* __restrict__ PO1,
    const float* __restrict__ ML, const float* __restrict__ lamp,
    u16* __restrict__ Mb) {
  const int g = threadIdx.x >> 5;          // 0..7 (row within block)
  const int dl = (threadIdx.x & 31) * 2;   // d offset
  const int ridx = blockIdx.x * 8 + g;     // (b,h,t): 0..65535
  const int b = ridx >> 15, rem = ridx & 32767, h = rem >> 11, t = rem & 2047;
  const float lam = *lamp;
  const size_t row1 = (size_t)(b * 32 + h) * 2048 + t;
  const size_t row2 = (size_t)(b * 32 + 16 + h) * 2048 + t;
  const float lA1 = ML[row1], lB1 = ML[131072 + row1];
  const float lA2 = ML[row2], lB2 = ML[131072 + row2];
  const float i1 = 1.0f / (lA1 + lB1);
  const float wa1 = lA1 * i1, wb1 = lB1 * i1;
  const float i2 = 1.0f / (lA2 + lB2);
  const float wa2 = lA2 * i2, wb2 = lB2 * i2;
  const ushort2 p01 = *(const ushort2*)&PO0[row1 * 64 + dl];
  const ushort2 p11 = *(const ushort2*)&PO1[row1 * 64 + dl];
  const ushort2 p02 = *(const ushort2*)&PO0[row2 * 64 + dl];
  const ushort2 p12 = *(const ushort2*)&PO1[row2 * 64 + dl];
  const float a1x = wa1 * bf2f(p01.x) + wb1 * bf2f(p11.x);
  const float a1y = wa1 * bf2f(p01.y) + wb1 * bf2f(p11.y);
  const float a2x = wa2 * bf2f(p02.x) + wb2 * bf2f(p12.x);
  const float a2y = wa2 * bf2f(p02.y) + wb2 * bf2f(p12.y);
  const float df0 = a1x - lam * a2x;
  const float df1 = a1y - lam * a2y;
  float ss = df0 * df0 + df1 * df1;
  ss += __shfl_xor(ss, 1, 64);
  ss += __shfl_xor(ss, 2, 64);
  ss += __shfl_xor(ss, 4, 64);
  ss += __shfl_xor(ss, 8, 64);
  ss += __shfl_xor(ss, 16, 64);
  const float rms = rsqrtf(ss * (1.0f / 64.0f) + 1e-5f);
  ushort2 o;
  o.x = f2bf(0.8f * df0 * rms);
  o.y = f2bf(0.8f * df1 * rms);
  *(ushort2*)&Mb[((size_t)(b * 2048 + t)) * 1024 + h * 64 + dl] = o;
}

// ---------------------------------------------------------------- launch
extern "C" void kernel_launch(void* const* d_in, const int* in_sizes, int n_in,
                              void* d_out, int out_size, void* d_ws, size_t ws_size,
                              hipStream_t stream) {
  const float* x = (const float*)d_in[0];
  const float* Wa = (const float*)d_in[1];
  const float* Wp = (const float*)d_in[2];
  const float* lq1 = (const float*)d_in[3];
  const float* lk1 = (const float*)d_in[4];
  const float* lq2 = (const float*)d_in[5];
  const float* lk2 = (const float*)d_in[6];
  if (ws_size < (size_t)(64u << 20)) return;  // need 64 MiB scratch

  char* ws = (char*)d_ws;
  u16* Qarr = (u16*)(ws);                        // 8 MiB
  u16* Karr = (u16*)(ws + (8u << 20));           // 8 MiB
  u16* VTarr = (u16*)(ws + (16u << 20));         // 8 MiB
  u16* WpT = (u16*)(ws + (24u << 20));           // 2 MiB
  char* arena = ws + (26u << 20);                // 38 MiB arena
  u16* xb = (u16*)(arena);                       // 8 MiB  (dead after gemm_qkv)
  u16* WaT = (u16*)(arena + (8u << 20));         // 6 MiB  (dead after gemm_qkv)
  float2* Tab = (float2*)(arena + (14u << 20));  // 256 KiB (dead after gemm_qkv)
  u16* PO0 = (u16*)(arena);                      // 16 MiB partial O (slot 0)
  u16* PO1 = (u16*)(arena + (16u << 20));        // 16 MiB partial O (slot 1)
  float* ML = (float*)(arena + (32u << 20));     // 1 MiB l per row per slot
  float* lamp = (float*)(arena + (33u << 20));   // 4 B lambda (survives attn)
  u16* Mbuf = Qarr;                              // 8 MiB (overlays Q after attn)

  prep_kernel<<<8321, 256, 0, stream>>>(x, Wa, Wp, lq1, lk1, lq2, lk2,
                                        xb, WaT, WpT, Tab, lamp);
  gemm_qkv_kernel<<<dim3(24, 16), 512, 0, stream>>>(xb, WaT, Qarr, Karr, VTarr, Tab);
  attn_kernel<<<dim3(16, 32, 2), 256, 0, stream>>>(Qarr, Karr, VTarr, PO0, PO1, ML);
  diff_rms_kernel<<<8192, 256, 0, stream>>>(PO0, PO1, ML, lamp, Mbuf);
  gemm_out_kernel<<<dim3(8, 64), 256, 0, stream>>>(Mbuf, WpT, (float*)d_out, 4096, 1024, 1024);
}

// Round 20
// 124.045 us; speedup vs baseline: 3.2077x; 1.5008x over previous
//
#include <hip/hip_runtime.h>

// MultiHeadDiffAttention: B=2, T=2048, C=1024, H=16 (v-heads), 2H=32 (q/k heads),
// D=32, Dv=64. prep -> qkv GEMM (256x128 tile, 512 thr, 2-phase dbuf, fused
// RoPE/V epilogue) -> KV-split swapped-QK^T flash attention (m=0 softmax,
// separate Ks/Vs/Os LDS arrays — verified round-17 configuration) ->
// merge+diff+RMS -> out GEMM (counted pipeline).

typedef unsigned short u16;
typedef __bf16 bf16x8 __attribute__((ext_vector_type(8)));
typedef float f32x4 __attribute__((ext_vector_type(4)));
typedef float f32x16 __attribute__((ext_vector_type(16)));
typedef unsigned u32x2 __attribute__((ext_vector_type(2)));

__device__ __forceinline__ u16 f2bf(float f) {
  return __builtin_bit_cast(u16, (__bf16)f);
}
__device__ __forceinline__ float bf2f(u16 u) {
  return (float)__builtin_bit_cast(__bf16, u);
}
__device__ __forceinline__ unsigned pk2(float a, float b) {
  return (unsigned)f2bf(a) | ((unsigned)f2bf(b) << 16);
}

// async global->LDS, 16B per lane. LDS dest must be wave-uniform-base + lane*16.
__device__ __forceinline__ void gload16(const u16* g, u16* l) {
  __builtin_amdgcn_global_load_lds(
      (const __attribute__((address_space(1))) unsigned int*)g,
      (__attribute__((address_space(3))) unsigned int*)l, 16, 0, 0);
}

// ------- fused prep: cvt x->bf16 + W transposes + rope table + lambda
// grid 8321: [0,4096) cvt; [4096,7168) Wa T; [7168,8192) Wp T;
// [8192,8320) rope cos/sin table (2048 x 16 float2); 8320: lambda scalar.
__device__ __forceinline__ void trans_body(const float* __restrict__ in,
                                           u16* __restrict__ out, int R, int Cn,
                                           int bx, int by, float (*tile)[33],
                                           int tx, int ty) {
  const int c0 = bx * 32, r0 = by * 32;
#pragma unroll
  for (int rr = 0; rr < 4; ++rr)
    tile[ty + rr * 8][tx] = in[(size_t)(r0 + ty + rr * 8) * Cn + c0 + tx];
  __syncthreads();
#pragma unroll
  for (int rr = 0; rr < 4; ++rr)
    out[(size_t)(c0 + ty + rr * 8) * R + r0 + tx] = f2bf(tile[tx][ty + rr * 8]);
}

__global__ __launch_bounds__(256) void prep_kernel(
    const float* __restrict__ x, const float* __restrict__ Wa,
    const float* __restrict__ Wp, const float* __restrict__ lq1,
    const float* __restrict__ lk1, const float* __restrict__ lq2,
    const float* __restrict__ lk2, u16* __restrict__ xb, u16* __restrict__ WaT,
    u16* __restrict__ WpT, float2* __restrict__ Tab, float* __restrict__ lamp) {
  __shared__ float tile[32][33];
  const int id = blockIdx.x;
  const int tx = threadIdx.x & 31, ty = threadIdx.x >> 5;
  if (id < 4096) {
    const int i = id * 256 + threadIdx.x;
    float4 v = ((const float4*)x)[i];
    ushort4 o;
    o.x = f2bf(v.x); o.y = f2bf(v.y); o.z = f2bf(v.z); o.w = f2bf(v.w);
    ((ushort4*)xb)[i] = o;
  } else if (id < 7168) {
    const int t = id - 4096;
    trans_body(Wa, WaT, 1024, 3072, t % 96, t / 96, tile, tx, ty);
  } else if (id < 8192) {
    const int t = id - 7168;
    trans_body(Wp, WpT, 1024, 1024, t & 31, t >> 5, tile, tx, ty);
  } else if (id < 8320) {
    const int idx = (id - 8192) * 256 + threadIdx.x;  // 0..32767
    const int t = idx >> 4, i = idx & 15;
    const float theta = exp2f(-0.83048202372184059f * (float)i);  // 10000^(-i/16)
    float sn, cs;
    sincosf((float)t * theta, &sn, &cs);
    Tab[idx] = make_float2(cs, sn);
  } else if (threadIdx.x == 0) {
    float d1 = 0.f, d2 = 0.f;
#pragma unroll
    for (int i = 0; i < 32; ++i) {
      d1 += lq1[i] * lk1[i];
      d2 += lq2[i] * lk2[i];
    }
    *lamp = expf(d1) - expf(d2) + 0.2f;
  }
}

// ------- qkv GEMM: 256x128 tile, 512 thr (8 waves 4x2, wave tile 64x64),
// 2-phase dbuf gload_lds, fused RoPE/V epilogue. grid (24,16) = 384 blocks.
__global__ __launch_bounds__(512, 4) void gemm_qkv_kernel(
    const u16* __restrict__ A, const u16* __restrict__ BT,
    u16* __restrict__ Q, u16* __restrict__ K, u16* __restrict__ VT,
    const float2* __restrict__ Tab) {
  const int Kdim = 1024;
  __shared__ u16 SH[24576];  // [2][As 8192 | Bs 4096] u16
  const int tid = threadIdx.x;
  const int l = tid & 63;
  const int w = tid >> 6;           // 0..7
  const int nwgx = gridDim.x;       // 24
  const int lin = blockIdx.x + nwgx * blockIdx.y;
  const int cpx = (nwgx * gridDim.y) >> 3;  // 48
  const int swz = (lin & 7) * cpx + (lin >> 3);
  const int bm = swz / nwgx, bn = swz % nwgx;   // bm 0..15, bn 0..23
  const int wm = w >> 1, wn = w & 1;            // wave tile 64x64
  const int rowA0 = bm * 256, rowB0 = bn * 128;
  const int r_ = tid >> 2;          // 0..127
  const int s_ = (tid & 3) * 8;
  const u16* Ag0 = &A[(size_t)(rowA0 + r_) * Kdim + s_];
  const u16* Ag1 = Ag0 + (size_t)128 * Kdim;
  const u16* Bg = &BT[(size_t)(rowB0 + r_) * Kdim + s_];
  f32x4 acc[4][4] = {};
  // prologue: stage buf 0 (k0=0)
  gload16(Ag0, &SH[tid * 8]);
  gload16(Ag1, &SH[4096 + tid * 8]);
  gload16(Bg, &SH[8192 + tid * 8]);
  __syncthreads();
  int cur = 0;
  for (int t = 0; t < 32; ++t) {
    const u16* Asc = SH + cur * 12288;
    const u16* Bsc = Asc + 8192;
    if (t + 1 < 32) {  // stage next tile into other buffer (async)
      u16* D = SH + (cur ^ 1) * 12288;
      const int k1 = (t + 1) * 32;
      gload16(Ag0 + k1, &D[tid * 8]);
      gload16(Ag1 + k1, &D[4096 + tid * 8]);
      gload16(Bg + k1, &D[8192 + tid * 8]);
    }
    bf16x8 a[4], b[4];
#pragma unroll
    for (int i = 0; i < 4; ++i)
      a[i] = *(const bf16x8*)&Asc[(wm * 64 + i * 16 + (l & 15)) * 32 + (l >> 4) * 8];
#pragma unroll
    for (int j = 0; j < 4; ++j)
      b[j] = *(const bf16x8*)&Bsc[(wn * 64 + j * 16 + (l & 15)) * 32 + (l >> 4) * 8];
    __builtin_amdgcn_s_setprio(1);
#pragma unroll
    for (int i = 0; i < 4; ++i)
#pragma unroll
      for (int j = 0; j < 4; ++j)
        acc[i][j] = __builtin_amdgcn_mfma_f32_16x16x32_bf16(a[i], b[j], acc[i][j], 0, 0, 0);
    __builtin_amdgcn_s_setprio(0);
    __syncthreads();  // drains this step's gloads AFTER compute; next buf ready
    cur ^= 1;
  }
  const int cr = (l >> 4) * 4;
  const int cc = l & 15;
  const int region = bn >> 3;   // 0=q, 1=k, 2=v (block-uniform)
  const int b_ = rowA0 >> 11, tb = rowA0 & 2047;
  if (region < 2) {
    const float qsc_ = (region == 0) ? 0.25503486f : 1.0f;  // 1/sqrt(32)*log2e | 1
    u16* dst = (region == 0) ? Q : K;
#pragma unroll
    for (int i = 0; i < 4; ++i) {
      const int trow0 = wm * 64 + i * 16 + cr;
#pragma unroll
      for (int j = 0; j < 4; ++j) {
        const int c = (bn & 7) * 128 + wn * 64 + j * 16 + cc;  // 0..1023
        const int hh = c >> 5, d = c & 31;
        const int ii = d >> 1;
        const float sgn = (d & 1) ? 1.0f : -1.0f;
        const size_t base = (size_t)(b_ * 32 + hh) * 2048;
#pragma unroll
        for (int r = 0; r < 4; ++r) {
          const int t = tb + trow0 + r;
          const float2 cs = Tab[t * 16 + ii];
          const float xv = acc[i][j][r];
          const float px = __shfl_xor(xv, 1, 64);
          dst[(base + t) * 32 + d] = f2bf((xv * cs.x + sgn * px * cs.y) * qsc_);
        }
      }
    }
  } else {
#pragma unroll
    for (int i = 0; i < 4; ++i) {
      const int t0 = tb + wm * 64 + i * 16 + cr;
#pragma unroll
      for (int j = 0; j < 4; ++j) {
        const int c3 = (bn & 7) * 128 + wn * 64 + j * 16 + cc;  // 0..1023
        const int hv = c3 >> 6, dv = c3 & 63;
        ushort4 ov;
        ov.x = f2bf(acc[i][j][0]);
        ov.y = f2bf(acc[i][j][1]);
        ov.z = f2bf(acc[i][j][2]);
        ov.w = f2bf(acc[i][j][3]);
        *(ushort4*)&VT[((size_t)(b_ * 16 + hv) * 64 + dv) * 2048 + t0] = ov;
      }
    }
  }
}

// --------------- out GEMM: 64x128 tile, counted-vmcnt pipeline, fp32 out.
__global__ __launch_bounds__(256, 3) void gemm_out_kernel(
    const u16* __restrict__ A, const u16* __restrict__ BT, float* __restrict__ Cout,
    int Mdim, int Ndim, int Kdim) {
  __shared__ u16 SH[24576];  // [4][As 2048 | Bs 4096] u16
  const int tid = threadIdx.x;
  const int l = tid & 63;
  const int w = tid >> 6;
  const int nwgx = gridDim.x;
  const int lin = blockIdx.x + nwgx * blockIdx.y;
  const int cpx = (nwgx * gridDim.y) >> 3;
  const int swz = (lin & 7) * cpx + (lin >> 3);
  const int bm = swz / nwgx, bn = swz % nwgx;
  const int wm = w >> 1, wn = w & 1;   // wave tile 32x64
  const int rowA0 = bm * 64, rowB0 = bn * 128;
  const int r_ = tid >> 2;
  const int s_ = (tid & 3) * 8;
  const u16* Ag = &A[(size_t)(rowA0 + r_) * Kdim + s_];
  const u16* Bg = &BT[(size_t)(rowB0 + r_) * Kdim + s_];
  const size_t rstride = (size_t)64 * Kdim;
  f32x4 acc[2][4] = {};
  const int nt = Kdim >> 5;  // 32
#pragma unroll
  for (int p = 0; p < 3; ++p) {
    u16* D = SH + p * 6144;
    const int k1 = p * 32;
    gload16(Ag + k1, &D[tid * 8]);
    gload16(Bg + k1, &D[2048 + tid * 8]);
    gload16(Bg + rstride + k1, &D[4096 + tid * 8]);
  }
  asm volatile("s_waitcnt vmcnt(6)" ::: "memory");
  __builtin_amdgcn_s_barrier();
  __builtin_amdgcn_sched_barrier(0);
  for (int t = 0; t < nt; ++t) {
    if (t + 3 < nt) {
      u16* D = SH + ((t + 3) & 3) * 6144;
      const int k1 = (t + 3) * 32;
      gload16(Ag + k1, &D[tid * 8]);
      gload16(Bg + k1, &D[2048 + tid * 8]);
      gload16(Bg + rstride + k1, &D[4096 + tid * 8]);
    }
    const u16* Asc = SH + (t & 3) * 6144;
    const u16* Bsc = Asc + 2048;
    bf16x8 a[2], b[4];
#pragma unroll
    for (int i = 0; i < 2; ++i)
      a[i] = *(const bf16x8*)&Asc[(wm * 32 + i * 16 + (l & 15)) * 32 + (l >> 4) * 8];
#pragma unroll
    for (int j = 0; j < 4; ++j)
      b[j] = *(const bf16x8*)&Bsc[(wn * 64 + j * 16 + (l & 15)) * 32 + (l >> 4) * 8];
    __builtin_amdgcn_s_setprio(1);
#pragma unroll
    for (int i = 0; i < 2; ++i)
#pragma unroll
      for (int j = 0; j < 4; ++j)
        acc[i][j] = __builtin_amdgcn_mfma_f32_16x16x32_bf16(a[i], b[j], acc[i][j], 0, 0, 0);
    __builtin_amdgcn_s_setprio(0);
    if (t + 1 < nt) {
      if (t + 3 < nt)
        asm volatile("s_waitcnt vmcnt(6)" ::: "memory");
      else if (t + 2 < nt)
        asm volatile("s_waitcnt vmcnt(3)" ::: "memory");
      else
        asm volatile("s_waitcnt vmcnt(0)" ::: "memory");
      __builtin_amdgcn_s_barrier();
      __builtin_amdgcn_sched_barrier(0);
    }
  }
  const int cr = (l >> 4) * 4;
  const int cc = l & 15;
#pragma unroll
  for (int i = 0; i < 2; ++i)
#pragma unroll
    for (int j = 0; j < 4; ++j)
#pragma unroll
      for (int r = 0; r < 4; ++r) {
        const int row = rowA0 + wm * 32 + i * 16 + cr + r;
        const int col = rowB0 + wn * 64 + j * 16 + cc;
        Cout[(size_t)row * Ndim + col] = acc[i][j][r];
      }
}

// ---------------------------------------------------------------- flash attention
// Swapped QK^T, 32x32x16 MFMA, exp2-domain, m=0 fixed softmax. KV-split:
// block x = (pp, hf); q-tile pp (slot=hf) and 15-pp (slot=hf^1); 17 steps/block.
// Separate Ks/Vs/Os LDS arrays (merged-overlay variant measured 2.4x slower).
__global__ __launch_bounds__(256, 4) void attn_kernel(const u16* __restrict__ Q,
                                                      const u16* __restrict__ K,
                                                      const u16* __restrict__ VT,
                                                      u16* __restrict__ PO0,
                                                      u16* __restrict__ PO1,
                                                      float* __restrict__ ML) {
  __shared__ u16 Ks[64 * 34];       // [k=64][d=32], stride 34 (17-bank step)
  __shared__ u16 Vs[64 * 66];       // [dv=64][k=64], stride 66 (33-bank step)
  __shared__ u16 Os[4 * 32 * 66];   // per-wave O staging
  const int tid = threadIdx.x, l = tid & 63, w = tid >> 6;
  const int pp = blockIdx.x & 7, hf = blockIdx.x >> 3;
  const int h = blockIdx.y, b = blockIdx.z;
  const size_t qkbase = (size_t)(b * 32 + h) * 2048;
  const size_t vtb = (size_t)(b * 16 + (h & 15)) * 64;
  const int lq = l & 31, hi = l >> 5;
  const f32x16 z16 = {};
  const int krow = tid >> 2, ksl = (tid & 3) * 8;   // K tile: 1 uint4/thread
  const int dva = tid >> 3, vsl = (tid & 7) * 8;    // V tile: 2 uint4/thread
  const int dvb = dva + 32;
  const __bf16 one1 = (__bf16)1.0f;
  const bf16x8 ones = {one1, one1, one1, one1, one1, one1, one1, one1};

  for (int halfidx = 0; halfidx < 2; ++halfidx) {
    const int qt = halfidx ? (15 - pp) : pp;
    const int slot = hf ^ halfidx;
    const int s_begin = slot ? (qt + 1) : 0;
    const int s_end = slot ? (2 * qt + 2) : (qt + 1);
    const int q0 = qt * 128;
    const int qw = q0 + w * 32;
    const int q = qw + lq;
    const bf16x8 qf0 = *(const bf16x8*)&Q[(qkbase + q) * 32 + hi * 8];
    const bf16x8 qf1 = *(const bf16x8*)&Q[(qkbase + q) * 32 + 16 + hi * 8];
    f32x16 olo = {}, ohi = {}, lacc = {};
    // prologue prefetch into regs
    uint4 kreg = *(const uint4*)&K[(qkbase + s_begin * 64 + krow) * 32 + ksl];
    uint4 vreg0 = *(const uint4*)&VT[(vtb + dva) * 2048 + s_begin * 64 + vsl];
    uint4 vreg1 = *(const uint4*)&VT[(vtb + dvb) * 2048 + s_begin * 64 + vsl];
    for (int s = s_begin; s < s_end; ++s) {
      const int kb = s * 64;
      *(uint4*)&Ks[krow * 34 + ksl] = kreg;
      *(uint4*)&Vs[dva * 66 + vsl] = vreg0;
      *(uint4*)&Vs[dvb * 66 + vsl] = vreg1;
      // prefetch next step (issued before barrier; latency hides under compute)
      const int sn = (s + 1 < s_end) ? (s + 1) : s;
      kreg = *(const uint4*)&K[(qkbase + sn * 64 + krow) * 32 + ksl];
      vreg0 = *(const uint4*)&VT[(vtb + dva) * 2048 + sn * 64 + vsl];
      vreg1 = *(const uint4*)&VT[(vtb + dvb) * 2048 + sn * 64 + vsl];
      __syncthreads();
      if (qw + 31 >= kb) {  // wave-uniform skip of fully-masked waves
        // S^T[k][q] = K·Q^T (pre-scaled, exp2 domain)
        f32x16 s0_, s1_;
        {
          const bf16x8 ka0 = *(const bf16x8*)&Ks[lq * 34 + hi * 8];
          const bf16x8 ka1 = *(const bf16x8*)&Ks[lq * 34 + 16 + hi * 8];
          const bf16x8 kc0 = *(const bf16x8*)&Ks[(32 + lq) * 34 + hi * 8];
          const bf16x8 kc1 = *(const bf16x8*)&Ks[(32 + lq) * 34 + 16 + hi * 8];
          __builtin_amdgcn_s_setprio(1);
          s0_ = __builtin_amdgcn_mfma_f32_32x32x16_bf16(ka0, qf0, z16, 0, 0, 0);
          s0_ = __builtin_amdgcn_mfma_f32_32x32x16_bf16(ka1, qf1, s0_, 0, 0, 0);
          s1_ = __builtin_amdgcn_mfma_f32_32x32x16_bf16(kc0, qf0, z16, 0, 0, 0);
          s1_ = __builtin_amdgcn_mfma_f32_32x32x16_bf16(kc1, qf1, s1_, 0, 0, 0);
          __builtin_amdgcn_s_setprio(0);
        }
        const bool nm = (kb + 63 > qw);
        if (nm) {
#pragma unroll
          for (int r = 0; r < 16; ++r) {
            const int kr = (r & 3) + 8 * (r >> 2) + 4 * hi;
            if (kb + kr > q) s0_[r] = -1e30f;
            if (kb + 32 + kr > q) s1_[r] = -1e30f;
          }
        }
        // P = exp2(S) directly (no max subtraction); masked -> exp2(-1e30)=0
#pragma unroll
        for (int r = 0; r < 16; ++r) {
          s0_[r] = __builtin_amdgcn_exp2f(s0_[r]);
          s1_[r] = __builtin_amdgcn_exp2f(s1_[r]);
        }
        // pack P -> bf16 words
        unsigned pw[16];
#pragma unroll
        for (int j = 0; j < 8; ++j) {
          pw[j] = pk2(s0_[2 * j], s0_[2 * j + 1]);
          pw[8 + j] = pk2(s1_[2 * j], s1_[2 * j + 1]);
        }
        // half-exchange -> P^T B-fragments
        bf16x8 pa[4];
#pragma unroll
        for (int fidx = 0; fidx < 4; ++fidx) {
          const unsigned* wt = &pw[fidx * 4];
          union { unsigned u[4]; bf16x8 v; } fr;
#if __has_builtin(__builtin_amdgcn_permlane32_swap)
          const u32x2 rA = __builtin_amdgcn_permlane32_swap(wt[0], wt[2], false, false);
          const u32x2 rB = __builtin_amdgcn_permlane32_swap(wt[1], wt[3], false, false);
          fr.u[0] = rA[0]; fr.u[1] = rB[0]; fr.u[2] = rA[1]; fr.u[3] = rB[1];
#else
          const unsigned ua = hi ? wt[0] : wt[2];
          const unsigned ub = hi ? wt[1] : wt[3];
          const unsigned sa = __shfl_xor(ua, 32, 64);
          const unsigned sb = __shfl_xor(ub, 32, 64);
          fr.u[0] = hi ? sa : wt[0];
          fr.u[1] = hi ? sb : wt[1];
          fr.u[2] = hi ? wt[2] : sa;
          fr.u[3] = hi ? wt[3] : sb;
#endif
          pa[fidx] = fr.v;
        }
        // O^T += V^T·P^T; row-sums via ones-fragment on the MFMA pipe
        __builtin_amdgcn_s_setprio(1);
#pragma unroll
        for (int ks = 0; ks < 4; ++ks) {
          const bf16x8 va = *(const bf16x8*)&Vs[lq * 66 + ks * 16 + hi * 8];
          const bf16x8 vb = *(const bf16x8*)&Vs[(32 + lq) * 66 + ks * 16 + hi * 8];
          olo = __builtin_amdgcn_mfma_f32_32x32x16_bf16(va, pa[ks], olo, 0, 0, 0);
          ohi = __builtin_amdgcn_mfma_f32_32x32x16_bf16(vb, pa[ks], ohi, 0, 0, 0);
          lacc = __builtin_amdgcn_mfma_f32_32x32x16_bf16(ones, pa[ks], lacc, 0, 0, 0);
        }
        __builtin_amdgcn_s_setprio(0);
      }
      __syncthreads();
    }
    // epilogue: write l + self-normalized partial O (bf16, coalesced)
    const float lsum = lacc[0];
    const float inv = (lsum > 0.f) ? (1.0f / lsum) : 0.f;
    if (hi == 0)
      ML[(size_t)slot * 131072 + qkbase + q] = lsum;
    u16* Ow = &Os[(w * 32 + lq) * 66];
#pragma unroll
    for (int g = 0; g < 4; ++g) {
      const int d0 = 8 * g + 4 * hi;
      *(unsigned*)&Ow[d0] = pk2(olo[4 * g] * inv, olo[4 * g + 1] * inv);
      *(unsigned*)&Ow[d0 + 2] = pk2(olo[4 * g + 2] * inv, olo[4 * g + 3] * inv);
      *(unsigned*)&Ow[32 + d0] = pk2(ohi[4 * g] * inv, ohi[4 * g + 1] * inv);
      *(unsigned*)&Ow[32 + d0 + 2] = pk2(ohi[4 * g + 2] * inv, ohi[4 * g + 3] * inv);
    }
    __syncthreads();
    u16* PO = slot ? PO1 : PO0;
    for (int s2 = tid; s2 < 1024; s2 += 256) {
      const int wv = s2 >> 8, qq = (s2 >> 3) & 31, sl = (s2 & 7) * 8;
      *(uint4*)&PO[(qkbase + q0 + wv * 32 + qq) * 64 + sl] =
          *(const uint4*)&Os[(wv * 32 + qq) * 66 + sl];
    }
    __syncthreads();
  }
}

// ---------------------------------------- fused partial-merge + diff + RMS
__global__ __launch_bounds__(256) void diff_rms_kernel(
    const u16* __restrict__ PO0, const u16* __restrict__ PO1,
    const float* __restrict__ ML, const float* __restrict__ lamp,
    u16* __restrict__ Mb) {
  const int g = threadIdx.x >> 5;          // 0..7 (row within block)
  const int dl = (threadIdx.x & 31) * 2;   // d offset
  const int ridx = blockIdx.x * 8 + g;     // (b,h,t): 0..65535
  const int b = ridx >> 15, rem = ridx & 32767, h = rem >> 11, t = rem & 2047;
  const float lam = *lamp;
  const size_t row1 = (size_t)(b * 32 + h) * 2048 + t;
  const size_t row2 = (size_t)(b * 32 + 16 + h) * 2048 + t;
  const float lA1 = ML[row1], lB1 = ML[131072 + row1];
  const float lA2 = ML[row2], lB2 = ML[131072 + row2];
  const float i1 = 1.0f / (lA1 + lB1);
  const float wa1 = lA1 * i1, wb1 = lB1 * i1;
  const float i2 = 1.0f / (lA2 + lB2);
  const float wa2 = lA2 * i2, wb2 = lB2 * i2;
  const ushort2 p01 = *(const ushort2*)&PO0[row1 * 64 + dl];
  const ushort2 p11 = *(const ushort2*)&PO1[row1 * 64 + dl];
  const ushort2 p02 = *(const ushort2*)&PO0[row2 * 64 + dl];
  const ushort2 p12 = *(const ushort2*)&PO1[row2 * 64 + dl];
  const float a1x = wa1 * bf2f(p01.x) + wb1 * bf2f(p11.x);
  const float a1y = wa1 * bf2f(p01.y) + wb1 * bf2f(p11.y);
  const float a2x = wa2 * bf2f(p02.x) + wb2 * bf2f(p12.x);
  const float a2y = wa2 * bf2f(p02.y) + wb2 * bf2f(p12.y);
  const float df0 = a1x - lam * a2x;
  const float df1 = a1y - lam * a2y;
  float ss = df0 * df0 + df1 * df1;
  ss += __shfl_xor(ss, 1, 64);
  ss += __shfl_xor(ss, 2, 64);
  ss += __shfl_xor(ss, 4, 64);
  ss += __shfl_xor(ss, 8, 64);
  ss += __shfl_xor(ss, 16, 64);
  const float rms = rsqrtf(ss * (1.0f / 64.0f) + 1e-5f);
  ushort2 o;
  o.x = f2bf(0.8f * df0 * rms);
  o.y = f2bf(0.8f * df1 * rms);
  *(ushort2*)&Mb[((size_t)(b * 2048 + t)) * 1024 + h * 64 + dl] = o;
}

// ---------------------------------------------------------------- launch
extern "C" void kernel_launch(void* const* d_in, const int* in_sizes, int n_in,
                              void* d_out, int out_size, void* d_ws, size_t ws_size,
                              hipStream_t stream) {
  const float* x = (const float*)d_in[0];
  const float* Wa = (const float*)d_in[1];
  const float* Wp = (const float*)d_in[2];
  const float* lq1 = (const float*)d_in[3];
  const float* lk1 = (const float*)d_in[4];
  const float* lq2 = (const float*)d_in[5];
  const float* lk2 = (const float*)d_in[6];
  if (ws_size < (size_t)(64u << 20)) return;  // need 64 MiB scratch

  char* ws = (char*)d_ws;
  u16* Qarr = (u16*)(ws);                        // 8 MiB
  u16* Karr = (u16*)(ws + (8u << 20));           // 8 MiB
  u16* VTarr = (u16*)(ws + (16u << 20));         // 8 MiB
  u16* WpT = (u16*)(ws + (24u << 20));           // 2 MiB
  char* arena = ws + (26u << 20);                // 38 MiB arena
  u16* xb = (u16*)(arena);                       // 8 MiB  (dead after gemm_qkv)
  u16* WaT = (u16*)(arena + (8u << 20));         // 6 MiB  (dead after gemm_qkv)
  float2* Tab = (float2*)(arena + (14u << 20));  // 256 KiB (dead after gemm_qkv)
  u16* PO0 = (u16*)(arena);                      // 16 MiB partial O (slot 0)
  u16* PO1 = (u16*)(arena + (16u << 20));        // 16 MiB partial O (slot 1)
  float* ML = (float*)(arena + (32u << 20));     // 1 MiB l per row per slot
  float* lamp = (float*)(arena + (33u << 20));   // 4 B lambda (survives attn)
  u16* Mbuf = Qarr;                              // 8 MiB (overlays Q after attn)

  prep_kernel<<<8321, 256, 0, stream>>>(x, Wa, Wp, lq1, lk1, lq2, lk2,
                                        xb, WaT, WpT, Tab, lamp);
  gemm_qkv_kernel<<<dim3(24, 16), 512, 0, stream>>>(xb, WaT, Qarr, Karr, VTarr, Tab);
  attn_kernel<<<dim3(16, 32, 2), 256, 0, stream>>>(Qarr, Karr, VTarr, PO0, PO1, ML);
  diff_rms_kernel<<<8192, 256, 0, stream>>>(PO0, PO1, ML, lamp, Mbuf);
  gemm_out_kernel<<<dim3(8, 64), 256, 0, stream>>>(Mbuf, WpT, (float*)d_out, 4096, 1024, 1024);
}